// Round 5
// baseline (697.891 us; speedup 1.0000x reference)
//
#include <hip/hip_runtime.h>

#define Bn 4
#define Tn 512
#define Mn 16
#define Dn 128
#define Pn 128
#define Hn 4
#define SCALE 0.08838834764831845f  // 1 / (2*sqrt(32))
#define GRID_BLKS 1024

typedef unsigned short u16;
typedef unsigned int u32;
typedef short s16;
typedef __attribute__((ext_vector_type(8))) s16 bf16x8;   // 8 bf16 = 4 VGPRs
typedef __attribute__((ext_vector_type(4))) float f32x4;  // MFMA C/D

#define NWE (Mn * Pn * Dn)  // 262144 elems per weight tensor

__device__ __forceinline__ u16 f2b(float f) {  // fp32 -> bf16 rne
  u32 x; __builtin_memcpy(&x, &f, 4);
  x += 0x7fffu + ((x >> 16) & 1u);
  return (u16)(x >> 16);
}
__device__ __forceinline__ u32 pack2(float a, float b) {
  return (u32)f2b(a) | ((u32)f2b(b) << 16);
}
__device__ __forceinline__ bf16x8 ld8(const u16* p) {  // 16B frag load
  bf16x8 r; __builtin_memcpy(&r, p, 16); return r;
}
__device__ __forceinline__ f32x4 mfma16(bf16x8 a, bf16x8 b, f32x4 c) {
  // D rows (quad*4+reg) <- a's row index (l16 at load); cols (l16) <- b's row
  return __builtin_amdgcn_mfma_f32_16x16x32_bf16(a, b, c, 0, 0, 0);
}

// Manual grid barrier: safe because all GRID_BLKS blocks are co-resident by
// construction (4 blocks/CU x 256 CUs, <=128 VGPR via launch_bounds, 36.9KB
// LDS). Counters pre-zeroed by the lengths kernel (stream-ordered, so no
// init race; re-zeroed every replay). Device-scope fences handle cross-XCD
// L2 non-coherence (G16).
__device__ __forceinline__ void grid_barrier(int* bar) {
  __threadfence();      // release: my global writes visible device-wide
  __syncthreads();      // whole block arrived (incl. LDS read drain)
  if (threadIdx.x == 0) {
    atomicAdd(bar, 1);  // device-scope by default (m20)
    while (__hip_atomic_load(bar, __ATOMIC_ACQUIRE,
                             __HIP_MEMORY_SCOPE_AGENT) < GRID_BLKS) {
      __builtin_amdgcn_s_sleep(2);
    }
  }
  __syncthreads();
  __threadfence();      // acquire for all threads of the block
}

// ---------------------------------------------------------------- lengths ---
// Also zeroes the two grid-barrier counters (bar = lens+4) before fused runs.
__global__ void lengths_kernel(const void* __restrict__ mask,
                               int* __restrict__ len_out) {
  const int b = blockIdx.x;
  __shared__ int cnt[256];
  if (b == 0 && threadIdx.x < 2) len_out[4 + threadIdx.x] = 0;  // barrier init
  const u32 w0 = ((const u32*)mask)[0];
  const int mode = (w0 == 1u) ? 0 : (w0 == 0x3F800000u) ? 1
                 : (w0 == 0x3F803F80u) ? 2 : 3;
  int c = 0;
  for (int t = threadIdx.x; t < Tn; t += 256) {
    const size_t idx = ((size_t)b * Tn + t) * Mn;
    int nz;
    if (mode == 0)      nz = (((const int*)mask)[idx] != 0);
    else if (mode == 1) nz = (((const u32*)mask)[idx] != 0u);
    else if (mode == 2) nz = (((const u16*)mask)[idx] != 0);
    else                nz = (((const unsigned char*)mask)[idx] != 0);
    c += nz;
  }
  cnt[threadIdx.x] = c;
  __syncthreads();
  for (int s = 128; s > 0; s >>= 1) {
    if (threadIdx.x < (unsigned)s) cnt[threadIdx.x] += cnt[threadIdx.x + s];
    __syncthreads();
  }
  if (threadIdx.x == 0) len_out[b] = cnt[0];
}

// ------------------------------------------------------------ fused kernel ---
// One launch, 3 phases with manual grid barriers between:
//   P1 prep: f32->bf16 of inp/pos/W (grid-stride).
//   P2 proj: 1280 (tsel,m,rowtile) MFMA tiles, grid-stride over 1024 blocks.
//   P3 attn: flash, 1 q-tile per wave; qt = wv*4 + (blk>>8) puts work-units
//            {1..8} summing to exactly 72 per CU under stride-256 residency.
__global__ __launch_bounds__(256, 4) void fused(
    const float* __restrict__ inp, const float* __restrict__ pos,
    const float* __restrict__ Wq, const float* __restrict__ Wk,
    const float* __restrict__ Wv, const float* __restrict__ Wqt,
    const float* __restrict__ Wkt,
    const float* __restrict__ Bq, const float* __restrict__ Bk,
    const float* __restrict__ Bv, const float* __restrict__ Bqt,
    const float* __restrict__ Bkt,
    int* __restrict__ lens, u16* __restrict__ Xb, u16* __restrict__ Pb,
    u16* __restrict__ Wb, u16* __restrict__ Qa, u16* __restrict__ Ka,
    u16* __restrict__ Qb, u16* __restrict__ Kb, u16* __restrict__ Vt,
    float* __restrict__ out) {
  __shared__ __align__(16) u16 S1[128 * 72];  // 18.4KB: proj Xs / attn P slabs
  __shared__ __align__(16) u16 S2[128 * 72];  // 18.4KB: proj Ws

  const int tid = threadIdx.x;
  const int blk = blockIdx.x;
  const int wv = tid >> 6, lane = tid & 63;
  const int quad = lane >> 4, l16 = lane & 15;
  int* bar = lens + 4;

  // ============================ phase 1: prep ============================
  {  // f32 -> bf16, unit = 8 elems (2x float4 load -> 1x 16B store)
    const int NI8 = Bn * Tn * Mn * Dn / 8;  // 524288
    const int NP8 = Bn * Tn * Dn / 8;       // 32768
    const int NW8 = NWE / 8;                // 32768
    const int total = NI8 + NP8 + 5 * NW8;  // 720896
    for (int u = blk * 256 + tid; u < total; u += GRID_BLKS * 256) {
      const float* s; u16* d; int off;
      if (u < NI8) { s = inp; d = Xb; off = u; }
      else if (u < NI8 + NP8) { s = pos; d = Pb; off = u - NI8; }
      else {
        const int r = u - NI8 - NP8;
        const int w = r >> 15; off = r & (NW8 - 1);
        switch (w) {
          case 0:  s = Wq;  d = Wb;            break;
          case 1:  s = Wk;  d = Wb + NWE;      break;
          case 2:  s = Wv;  d = Wb + 2 * NWE;  break;
          case 3:  s = Wqt; d = Wb + 3 * NWE;  break;
          default: s = Wkt; d = Wb + 4 * NWE;  break;
        }
      }
      const float4 a0 = *(const float4*)(s + (size_t)off * 8);
      const float4 a1 = *(const float4*)(s + (size_t)off * 8 + 4);
      uint4 dd;
      dd.x = pack2(a0.x, a0.y); dd.y = pack2(a0.z, a0.w);
      dd.z = pack2(a1.x, a1.y); dd.w = pack2(a1.z, a1.w);
      *(uint4*)(d + (size_t)off * 8) = dd;
    }
  }
  grid_barrier(&bar[0]);

  // ============================ phase 2: proj ============================
  for (int ti = blk; ti < 1280; ti += GRID_BLKS) {
    const int tsel = ti % 5;
    const int m = (ti / 5) % Mn;
    const int rt0 = (ti / (5 * Mn)) * 128;

    const float* Bb; int usepos, doscale; u16* dst;
    switch (tsel) {
      case 0:  Bb = Bq;  usepos = 0; doscale = 1; dst = Qa; break;
      case 1:  Bb = Bk;  usepos = 0; doscale = 0; dst = Ka; break;
      case 2:  Bb = Bv;  usepos = 0; doscale = 0; dst = Vt; break;
      case 3:  Bb = Bqt; usepos = 1; doscale = 1; dst = Qb; break;
      default: Bb = Bkt; usepos = 1; doscale = 0; dst = Kb; break;
    }
    const u16* A = usepos ? Pb : Xb;
    const u16* Wsrc = Wb + (size_t)tsel * NWE + (size_t)m * Pn * Dn;
    const u16* Als = (tsel == 2) ? S1 : S2;  // V: A=X(rows t); else A=W(rows p)
    const u16* Bls = (tsel == 2) ? S2 : S1;

    f32x4 acc[2][8];
#pragma unroll
    for (int i = 0; i < 2; ++i)
#pragma unroll
      for (int n = 0; n < 8; ++n) acc[i][n] = (f32x4){0.f, 0.f, 0.f, 0.f};

    for (int kh = 0; kh < 2; ++kh) {
      bf16x8 xr[4], wr[4];
#pragma unroll
      for (int it = 0; it < 4; ++it) {
        const int c = tid + it * 256;
        const int row = c >> 3, c8 = (c & 7) * 8, col = kh * 64 + c8;
        const size_t sx = usepos ? ((size_t)(rt0 + row) * Dn + col)
                                 : (((size_t)(rt0 + row) * Mn + m) * Dn + col);
        xr[it] = ld8(A + sx);
      }
#pragma unroll
      for (int it = 0; it < 4; ++it) {
        const int c = tid + it * 256;
        const int row = c >> 3, c8 = (c & 7) * 8, col = kh * 64 + c8;
        wr[it] = ld8(Wsrc + (size_t)row * Dn + col);
      }
      __syncthreads();  // prior LDS reads (prev kh / prev tile) complete
#pragma unroll
      for (int it = 0; it < 4; ++it) {
        const int c = tid + it * 256;
        const int row = c >> 3, c8 = (c & 7) * 8;
        *(bf16x8*)&S1[row * 72 + c8] = xr[it];
      }
#pragma unroll
      for (int it = 0; it < 4; ++it) {
        const int c = tid + it * 256;
        const int row = c >> 3, c8 = (c & 7) * 8;
        *(bf16x8*)&S2[row * 72 + c8] = wr[it];
      }
      __syncthreads();
#pragma unroll
      for (int kc = 0; kc < 2; ++kc) {
        const int ko = kc * 32 + quad * 8;
        const bf16x8 a0 = ld8(&Als[(wv * 32 + l16) * 72 + ko]);
        const bf16x8 a1 = ld8(&Als[(wv * 32 + 16 + l16) * 72 + ko]);
#pragma unroll
        for (int n = 0; n < 8; ++n) {
          const bf16x8 bn = ld8(&Bls[(n * 16 + l16) * 72 + ko]);
          acc[0][n] = mfma16(a0, bn, acc[0][n]);
          acc[1][n] = mfma16(a1, bn, acc[1][n]);
        }
      }
    }

    const int b = rt0 >> 9;          // rowtile never crosses a batch boundary
    const int tb = rt0 & (Tn - 1);
    if (tsel == 2) {
      // V: acc[qs][n] -> rows t = tb+wv*32+qs*16+quad*4+reg, col e; Vt[bmh][e][t]
      const int tl0 = tb + wv * 32;
#pragma unroll
      for (int n = 0; n < 8; ++n) {
        const int h = n >> 1, e = (n & 1) * 16 + l16;
        const float bias = Bb[m * Pn + n * 16 + l16];
        const int bmh = (b * Mn + m) * Hn + h;
        const size_t rowv = ((size_t)bmh * 32 + e) * Tn;
#pragma unroll
        for (int qs = 0; qs < 2; ++qs) {
          const int t0 = tl0 + qs * 16 + quad * 4;
          uint2 d;
          d.x = pack2(acc[qs][n][0] + bias, acc[qs][n][1] + bias);
          d.y = pack2(acc[qs][n][2] + bias, acc[qs][n][3] + bias);
          *(uint2*)&dst[rowv + t0] = d;
        }
      }
    } else {
      // Q/K/Qb/Kb: acc[pf][tf] -> p = wv*32+pf*16+quad*4+reg, t = tb+tf*16+l16
      const int bmh = (b * Mn + m) * Hn + wv;
#pragma unroll
      for (int pf = 0; pf < 2; ++pf) {
        const int p0 = wv * 32 + pf * 16 + quad * 4;
        const float4 b4 = *(const float4*)&Bb[m * Pn + p0];
#pragma unroll
        for (int tf = 0; tf < 8; ++tf) {
          const int t = tb + tf * 16 + l16;
          float v0 = acc[pf][tf][0] + b4.x;
          float v1 = acc[pf][tf][1] + b4.y;
          float v2 = acc[pf][tf][2] + b4.z;
          float v3 = acc[pf][tf][3] + b4.w;
          if (doscale) { v0 *= SCALE; v1 *= SCALE; v2 *= SCALE; v3 *= SCALE; }
          uint2 d; d.x = pack2(v0, v1); d.y = pack2(v2, v3);
          *(uint2*)&dst[((size_t)bmh * Tn + t) * 32 + pf * 16 + quad * 4] = d;
        }
      }
    }
  }
  grid_barrier(&bar[1]);  // includes __syncthreads: S1 reads drained

  // ============================ phase 3: attn ============================
  {
    const int bmh = blk & 255;
    const int qt = wv * 4 + (blk >> 8);  // per-CU work sums to exactly 72 units
    const int b = bmh >> 6;              // Mn*Hn = 64
    const int len = lens[b];
    const int q0 = qt * 32;
    const size_t rowbase = (size_t)bmh * Tn;
    const size_t vbase = (size_t)bmh * 32 * Tn;
    u16* myPs = &S1[wv * 32 * 72];
    const int mm = (bmh >> 2) & (Mn - 1);
    const int h = bmh & (Hn - 1);

    bf16x8 qf[2][2];
#pragma unroll
    for (int qs = 0; qs < 2; ++qs) {
      const size_t r = (rowbase + q0 + qs * 16 + l16) * 32 + quad * 8;
      qf[qs][0] = ld8(Qa + r);
      qf[qs][1] = ld8(Qb + r);
    }

    f32x4 O[2][2];  // [qs][es], D rows = e (quad*4+reg), cols = q (l16)
#pragma unroll
    for (int qs = 0; qs < 2; ++qs)
#pragma unroll
      for (int es = 0; es < 2; ++es) O[qs][es] = (f32x4){0.f, 0.f, 0.f, 0.f};
    float mrow[2] = {-1e30f, -1e30f}, lsum[2] = {0.f, 0.f};

    const int s_hi = min(q0 + 32, len);  // len >= T/2 >= 1
    for (int s0 = 0; s0 < s_hi; s0 += 64) {
      f32x4 S[2][4];
      __builtin_amdgcn_s_setprio(1);
#pragma unroll
      for (int st = 0; st < 4; ++st) {
        const size_t kr = (rowbase + s0 + st * 16 + l16) * 32 + quad * 8;
        const bf16x8 k0 = ld8(Ka + kr);
        const bf16x8 k1 = ld8(Kb + kr);
#pragma unroll
        for (int qs = 0; qs < 2; ++qs)
          S[qs][st] = mfma16(k1, qf[qs][1],
                             mfma16(k0, qf[qs][0], (f32x4){0.f, 0.f, 0.f, 0.f}));
      }
      __builtin_amdgcn_s_setprio(0);

#pragma unroll
      for (int qs = 0; qs < 2; ++qs) {
        const int q = q0 + qs * 16 + l16;
        const int qcap = min(q, len - 1);  // valid <=> s <= qcap
        const int sb = s0 + quad * 4;
        float cmax = -1e30f;
#pragma unroll
        for (int st = 0; st < 4; ++st)
#pragma unroll
          for (int reg = 0; reg < 4; ++reg) {
            const int s = sb + st * 16 + reg;
            const float v = (s <= qcap) ? S[qs][st][reg] : -1e30f;
            S[qs][st][reg] = v;
            cmax = fmaxf(cmax, v);
          }
        cmax = fmaxf(cmax, __shfl_xor(cmax, 16));
        cmax = fmaxf(cmax, __shfl_xor(cmax, 32));
        const float mnew = fmaxf(mrow[qs], cmax);  // finite: chunk has a valid key
        const float alpha = __expf(mrow[qs] - mnew);
        mrow[qs] = mnew;
        float rsum = 0.f;
        u32 pk[4][2];
#pragma unroll
        for (int st = 0; st < 4; ++st) {
          const float p0 = __expf(S[qs][st][0] - mnew);
          const float p1 = __expf(S[qs][st][1] - mnew);
          const float p2 = __expf(S[qs][st][2] - mnew);
          const float p3 = __expf(S[qs][st][3] - mnew);
          rsum += (p0 + p1) + (p2 + p3);
          pk[st][0] = pack2(p0, p1);
          pk[st][1] = pack2(p2, p3);
        }
        rsum += __shfl_xor(rsum, 16);
        rsum += __shfl_xor(rsum, 32);
        lsum[qs] = lsum[qs] * alpha + rsum;
#pragma unroll
        for (int es = 0; es < 2; ++es)
#pragma unroll
          for (int reg = 0; reg < 4; ++reg) O[qs][es][reg] *= alpha;
        // P -> private per-wave LDS slab (same-wave ordering via lgkmcnt)
#pragma unroll
        for (int st = 0; st < 4; ++st) {
          uint2 d; d.x = pk[st][0]; d.y = pk[st][1];
          *(uint2*)&myPs[(qs * 16 + l16) * 72 + st * 16 + quad * 4] = d;
        }
      }

      // O^T += V^T . P
      __builtin_amdgcn_s_setprio(1);
#pragma unroll
      for (int kc = 0; kc < 2; ++kc) {
        const int ko = kc * 32 + quad * 8;
        const bf16x8 pf0 = ld8(&myPs[l16 * 72 + ko]);
        const bf16x8 pf1 = ld8(&myPs[(16 + l16) * 72 + ko]);
        const bf16x8 vf0 = ld8(Vt + vbase + (size_t)l16 * Tn + s0 + ko);
        const bf16x8 vf1 = ld8(Vt + vbase + (size_t)(16 + l16) * Tn + s0 + ko);
        O[0][0] = mfma16(vf0, pf0, O[0][0]);
        O[0][1] = mfma16(vf1, pf0, O[0][1]);
        O[1][0] = mfma16(vf0, pf1, O[1][0]);
        O[1][1] = mfma16(vf1, pf1, O[1][1]);
      }
      __builtin_amdgcn_s_setprio(0);
    }

    // epilogue: lane q = qs*16+l16, e = es*16+quad*4+reg
#pragma unroll
    for (int qs = 0; qs < 2; ++qs) {
      const float linv = 1.0f / lsum[qs];
      const int t = q0 + qs * 16 + l16;
      const size_t ob = (((size_t)b * Tn + t) * Mn + mm) * Pn + h * 32 + quad * 4;
#pragma unroll
      for (int es = 0; es < 2; ++es) {
        float4 o;
        o.x = O[qs][es][0] * linv; o.y = O[qs][es][1] * linv;
        o.z = O[qs][es][2] * linv; o.w = O[qs][es][3] * linv;
        *(float4*)&out[ob + es * 16] = o;
      }
    }
  }
}

// ------------------------------------------------------------------ launch ---
extern "C" void kernel_launch(void* const* d_in, const int* in_sizes, int n_in,
                              void* d_out, int out_size, void* d_ws, size_t ws_size,
                              hipStream_t stream) {
  const float* inp = (const float*)d_in[0];
  const float* pos = (const float*)d_in[1];
  const void* mask = d_in[2];
  const float* Wq  = (const float*)d_in[3];
  const float* Bq  = (const float*)d_in[4];
  const float* Wk  = (const float*)d_in[5];
  const float* Bk  = (const float*)d_in[6];
  const float* Wv  = (const float*)d_in[7];
  const float* Bv  = (const float*)d_in[8];
  const float* Wqt = (const float*)d_in[9];
  const float* Bqt = (const float*)d_in[10];
  const float* Wkt = (const float*)d_in[11];
  const float* Bkt = (const float*)d_in[12];
  float* out = (float*)d_out;

  const size_t nA = (size_t)Bn * Mn * Hn * Tn * 32;  // 4.19M elems per array
  u16* Qa = (u16*)d_ws;
  u16* Ka = Qa + nA;
  u16* Qb = Ka + nA;
  u16* Kb = Qb + nA;
  u16* Vt = Kb + nA;
  int* lens = (int*)(Vt + nA);           // lens[0..3]; lens[4..5] = barrier
  u16* Xb = (u16*)(lens + 8);            // keep 16B alignment
  u16* Pb = Xb + (size_t)Bn * Tn * Mn * Dn;
  u16* Wb = Pb + (size_t)Bn * Tn * Dn;

  lengths_kernel<<<Bn, 256, 0, stream>>>(mask, lens);
  fused<<<GRID_BLKS, 256, 0, stream>>>(
      inp, pos, Wq, Wk, Wv, Wqt, Wkt, Bq, Bk, Bv, Bqt, Bkt,
      lens, Xb, Pb, Wb, Qa, Ka, Qb, Kb, Vt, out);
}

// Round 6
// 138.794 us; speedup vs baseline: 5.0282x; 5.0282x over previous
//
#include <hip/hip_runtime.h>

#define Bn 4
#define Tn 512
#define Mn 16
#define Dn 128
#define Pn 128
#define Hn 4
#define SCALE 0.08838834764831845f  // 1 / (2*sqrt(32))

typedef unsigned short u16;
typedef unsigned int u32;
typedef short s16;
typedef __attribute__((ext_vector_type(8))) s16 bf16x8;   // 8 bf16 = 4 VGPRs
typedef __attribute__((ext_vector_type(4))) float f32x4;  // MFMA C/D

__device__ __forceinline__ u16 f2b(float f) {  // fp32 -> bf16 rne
  u32 x; __builtin_memcpy(&x, &f, 4);
  x += 0x7fffu + ((x >> 16) & 1u);
  return (u16)(x >> 16);
}
__device__ __forceinline__ u32 pack2(float a, float b) {
  return (u32)f2b(a) | ((u32)f2b(b) << 16);
}
__device__ __forceinline__ bf16x8 ld8(const u16* p) {  // 16B frag load
  bf16x8 r; __builtin_memcpy(&r, p, 16); return r;
}
__device__ __forceinline__ f32x4 mfma16(bf16x8 a, bf16x8 b, f32x4 c) {
  // D rows (quad*4+reg) <- a's row index (l16 at load); cols (l16) <- b's row
  return __builtin_amdgcn_mfma_f32_16x16x32_bf16(a, b, c, 0, 0, 0);
}

// --------------------------------------------------------- merged projection ---
// Block families (512 blocks total, 2 blocks/CU @ 71.7KB LDS):
//   A (bid<256):  (m, rowtile) -> Q, K, V from inp  (X staged+converted once)
//   B (bid>=256): (m, rowtile) -> Qb, Kb from pos
// X full-width in LDS [128][136] (272B rows -> 2-way bank, free); W halves
// double-buffered [2][128][72] with register prefetch of the next half during
// the current half's MFMA (one __syncthreads per step). f32->bf16 conversion
// happens exactly once per element (prep kernel + workspace roundtrip gone).
__global__ __launch_bounds__(256, 2) void proj_merged(
    const float* __restrict__ inp, const float* __restrict__ pos,
    const float* __restrict__ Wq, const float* __restrict__ Wk,
    const float* __restrict__ Wv, const float* __restrict__ Wqt,
    const float* __restrict__ Wkt,
    const float* __restrict__ Bq, const float* __restrict__ Bk,
    const float* __restrict__ Bv, const float* __restrict__ Bqt,
    const float* __restrict__ Bkt,
    u16* __restrict__ Qa, u16* __restrict__ Ka, u16* __restrict__ Qb,
    u16* __restrict__ Kb, u16* __restrict__ Vt) {
  __shared__ __align__(16) u16 Xs[128 * 136];     // 34.8KB
  __shared__ __align__(16) u16 Ws2[2][128 * 72];  // 36.9KB

  const int tid = threadIdx.x;
  const int bid = blockIdx.x;
  const bool isA = bid < 256;
  const int sub = bid & 255;
  const int m = sub & 15;
  const int rt0 = (sub >> 4) * 128;

  const int wv = tid >> 6, lane = tid & 63;
  const int quad = lane >> 4, l16 = lane & 15;

  const float* Wlist[3]; const float* Blist[3]; u16* dstlist[3];
  int ntsel;
  const size_t wofs = (size_t)m * Pn * Dn;
  if (isA) {
    Wlist[0] = Wq + wofs; Wlist[1] = Wk + wofs; Wlist[2] = Wv + wofs;
    Blist[0] = Bq; Blist[1] = Bk; Blist[2] = Bv;
    dstlist[0] = Qa; dstlist[1] = Ka; dstlist[2] = Vt;
    ntsel = 3;
  } else {
    Wlist[0] = Wqt + wofs; Wlist[1] = Wkt + wofs; Wlist[2] = Wkt + wofs;
    Blist[0] = Bqt; Blist[1] = Bkt; Blist[2] = Bkt;
    dstlist[0] = Qb; dstlist[1] = Kb; dstlist[2] = Kb;
    ntsel = 2;
  }
  const int nsteps = ntsel * 2;
  const float* Asrc = isA ? inp : pos;

  // ---- stage X full 128x128 (f32 -> bf16 inline, once) ----
#pragma unroll
  for (int it = 0; it < 16; ++it) {
    const int c = tid + it * 256;
    const int row = c >> 5, col4 = (c & 31) * 4;
    const size_t sx = isA ? (((size_t)(rt0 + row) * Mn + m) * Dn + col4)
                          : ((size_t)(rt0 + row) * Dn + col4);
    const float4 x = *(const float4*)(Asrc + sx);
    ushort4 h; h.x = f2b(x.x); h.y = f2b(x.y); h.z = f2b(x.z); h.w = f2b(x.w);
    *(ushort4*)&Xs[row * 136 + col4] = h;
  }
  // ---- stage W step 0 (tsel 0, kh 0) ----
  {
    float4 wrg[8];
#pragma unroll
    for (int it = 0; it < 8; ++it) {
      const int c = tid + it * 256;
      const int row = c >> 4, col4 = (c & 15) * 4;
      wrg[it] = *(const float4*)(Wlist[0] + (size_t)row * Dn + col4);
    }
#pragma unroll
    for (int it = 0; it < 8; ++it) {
      const int c = tid + it * 256;
      const int row = c >> 4, col4 = (c & 15) * 4;
      ushort4 h; h.x = f2b(wrg[it].x); h.y = f2b(wrg[it].y);
      h.z = f2b(wrg[it].z); h.w = f2b(wrg[it].w);
      *(ushort4*)&Ws2[0][row * 72 + col4] = h;
    }
  }
  __syncthreads();

  const int b = rt0 >> 9;            // rowtile never crosses a batch boundary
  const int tb = rt0 & (Tn - 1);

#pragma unroll
  for (int tsel = 0; tsel < 3; ++tsel) {
    if (tsel >= ntsel) break;
    const bool isV = isA && (tsel == 2);

    f32x4 acc[2][8];
#pragma unroll
    for (int i = 0; i < 2; ++i)
#pragma unroll
      for (int n = 0; n < 8; ++n) acc[i][n] = (f32x4){0.f, 0.f, 0.f, 0.f};

#pragma unroll
    for (int kh = 0; kh < 2; ++kh) {
      const int s = tsel * 2 + kh;
      const bool more = (s + 1) < nsteps;
      float4 wrg[8];
      if (more) {  // register-prefetch next W half during this half's MFMA
        const int t1 = (s + 1) >> 1, kh1 = (s + 1) & 1;
        const float* Wn = Wlist[t1];
#pragma unroll
        for (int it = 0; it < 8; ++it) {
          const int c = tid + it * 256;
          const int row = c >> 4, col4 = (c & 15) * 4;
          wrg[it] = *(const float4*)(Wn + (size_t)row * Dn + kh1 * 64 + col4);
        }
      }
      const u16* Wcur = Ws2[s & 1];
#pragma unroll
      for (int kc = 0; kc < 2; ++kc) {
        const int wco = kc * 32 + quad * 8;
        const int xco = kh * 64 + wco;
        bf16x8 a0, a1;
        if (isV) {  // A = X rows (t), B = W rows (p)
          a0 = ld8(&Xs[(wv * 32 + l16) * 136 + xco]);
          a1 = ld8(&Xs[(wv * 32 + 16 + l16) * 136 + xco]);
        } else {    // A = W rows (p), B = X rows (t)
          a0 = ld8(&Wcur[(wv * 32 + l16) * 72 + wco]);
          a1 = ld8(&Wcur[(wv * 32 + 16 + l16) * 72 + wco]);
        }
#pragma unroll
        for (int n = 0; n < 8; ++n) {
          const bf16x8 bn = isV ? ld8(&Wcur[(n * 16 + l16) * 72 + wco])
                                : ld8(&Xs[(n * 16 + l16) * 136 + xco]);
          acc[0][n] = mfma16(a0, bn, acc[0][n]);
          acc[1][n] = mfma16(a1, bn, acc[1][n]);
        }
      }
      if (more) {  // convert + write prefetched half into the other buffer
        u16* Wnxt = Ws2[(s + 1) & 1];
#pragma unroll
        for (int it = 0; it < 8; ++it) {
          const int c = tid + it * 256;
          const int row = c >> 4, col4 = (c & 15) * 4;
          ushort4 h; h.x = f2b(wrg[it].x); h.y = f2b(wrg[it].y);
          h.z = f2b(wrg[it].z); h.w = f2b(wrg[it].w);
          *(ushort4*)&Wnxt[row * 72 + col4] = h;
        }
      }
      __syncthreads();
    }

    // ---- epilogue (verbatim-verified layouts) ----
    const float* Bb = Blist[tsel];
    u16* dst = dstlist[tsel];
    const int doscale = (tsel == 0);
    if (isV) {
      // V: acc[qs][n] -> rows t = tb+wv*32+qs*16+quad*4+reg, col e; Vt[bmh][e][t]
      const int tl0 = tb + wv * 32;
#pragma unroll
      for (int n = 0; n < 8; ++n) {
        const int h = n >> 1, e = (n & 1) * 16 + l16;
        const float bias = Bb[m * Pn + n * 16 + l16];
        const int bmh = (b * Mn + m) * Hn + h;
        const size_t rowv = ((size_t)bmh * 32 + e) * Tn;
#pragma unroll
        for (int qs = 0; qs < 2; ++qs) {
          const int t0 = tl0 + qs * 16 + quad * 4;
          uint2 d;
          d.x = pack2(acc[qs][n][0] + bias, acc[qs][n][1] + bias);
          d.y = pack2(acc[qs][n][2] + bias, acc[qs][n][3] + bias);
          *(uint2*)&dst[rowv + t0] = d;
        }
      }
    } else {
      // Q/K/Qb/Kb: acc[pf][tf] -> p = wv*32+pf*16+quad*4+reg, t = tb+tf*16+l16
      const int bmh = (b * Mn + m) * Hn + wv;
#pragma unroll
      for (int pf = 0; pf < 2; ++pf) {
        const int p0 = wv * 32 + pf * 16 + quad * 4;
        const float4 b4 = *(const float4*)&Bb[m * Pn + p0];
#pragma unroll
        for (int tf = 0; tf < 8; ++tf) {
          const int t = tb + tf * 16 + l16;
          float v0 = acc[pf][tf][0] + b4.x;
          float v1 = acc[pf][tf][1] + b4.y;
          float v2 = acc[pf][tf][2] + b4.z;
          float v3 = acc[pf][tf][3] + b4.w;
          if (doscale) { v0 *= SCALE; v1 *= SCALE; v2 *= SCALE; v3 *= SCALE; }
          uint2 d; d.x = pack2(v0, v1); d.y = pack2(v2, v3);
          *(uint2*)&dst[((size_t)bmh * Tn + t) * 32 + pf * 16 + quad * 4] = d;
        }
      }
    }
  }
}

// ------------------------------------------------------- attention (flash) ---
// R5-phase3 body (numerically verified): wave-autonomous, 1 q-tile per wave,
// balanced qt = wv*4 + (blk>>8) (72 work-units per CU under stride-256
// residency). Lengths computed inline per-wave via shuffle reduce (no LDS,
// no syncs, mask is L2-resident) -> lengths dispatch eliminated.
__global__ __launch_bounds__(256, 4) void attn_flash(
    const void* __restrict__ mask,
    const u16* __restrict__ Qa, const u16* __restrict__ Ka,
    const u16* __restrict__ Qb, const u16* __restrict__ Kb,
    const u16* __restrict__ Vt, float* __restrict__ out) {
  __shared__ __align__(16) u16 Ps[4 * 32 * 72];  // 18.4KB, per-wave slabs

  const int tid = threadIdx.x;
  const int blk = blockIdx.x;
  const int wv = tid >> 6, lane = tid & 63;
  const int quad = lane >> 4, l16 = lane & 15;

  const int bmh = blk & 255;
  const int qt = wv * 4 + (blk >> 8);  // per-CU work sums to exactly 72 units
  const int b = bmh >> 6;              // Mn*Hn = 64

  // inline per-wave length (shuffle reduce; 8 coalesced strided loads/lane)
  const u32 w0 = ((const u32*)mask)[0];
  const int mode = (w0 == 1u) ? 0 : (w0 == 0x3F800000u) ? 1
                 : (w0 == 0x3F803F80u) ? 2 : 3;
  int c = 0;
  for (int t = lane; t < Tn; t += 64) {
    const size_t idx = ((size_t)b * Tn + t) * Mn;
    int nz;
    if (mode == 0)      nz = (((const int*)mask)[idx] != 0);
    else if (mode == 1) nz = (((const u32*)mask)[idx] != 0u);
    else if (mode == 2) nz = (((const u16*)mask)[idx] != 0);
    else                nz = (((const unsigned char*)mask)[idx] != 0);
    c += nz;
  }
  c += __shfl_xor(c, 1);  c += __shfl_xor(c, 2);  c += __shfl_xor(c, 4);
  c += __shfl_xor(c, 8);  c += __shfl_xor(c, 16); c += __shfl_xor(c, 32);
  const int len = c;

  const int q0 = qt * 32;
  const size_t rowbase = (size_t)bmh * Tn;
  const size_t vbase = (size_t)bmh * 32 * Tn;
  u16* myPs = &Ps[wv * 32 * 72];
  const int mm = (bmh >> 2) & (Mn - 1);
  const int h = bmh & (Hn - 1);

  bf16x8 qf[2][2];
#pragma unroll
  for (int qs = 0; qs < 2; ++qs) {
    const size_t r = (rowbase + q0 + qs * 16 + l16) * 32 + quad * 8;
    qf[qs][0] = ld8(Qa + r);
    qf[qs][1] = ld8(Qb + r);
  }

  f32x4 O[2][2];  // [qs][es], D rows = e (quad*4+reg), cols = q (l16)
#pragma unroll
  for (int qs = 0; qs < 2; ++qs)
#pragma unroll
    for (int es = 0; es < 2; ++es) O[qs][es] = (f32x4){0.f, 0.f, 0.f, 0.f};
  float mrow[2] = {-1e30f, -1e30f}, lsum[2] = {0.f, 0.f};

  const int s_hi = min(q0 + 32, len);  // len >= T/2 >= 1
  for (int s0 = 0; s0 < s_hi; s0 += 64) {
    f32x4 S[2][4];
    __builtin_amdgcn_s_setprio(1);
#pragma unroll
    for (int st = 0; st < 4; ++st) {
      const size_t kr = (rowbase + s0 + st * 16 + l16) * 32 + quad * 8;
      const bf16x8 k0 = ld8(Ka + kr);
      const bf16x8 k1 = ld8(Kb + kr);
#pragma unroll
      for (int qs = 0; qs < 2; ++qs)
        S[qs][st] = mfma16(k1, qf[qs][1],
                           mfma16(k0, qf[qs][0], (f32x4){0.f, 0.f, 0.f, 0.f}));
    }
    __builtin_amdgcn_s_setprio(0);

#pragma unroll
    for (int qs = 0; qs < 2; ++qs) {
      const int q = q0 + qs * 16 + l16;
      const int qcap = min(q, len - 1);  // valid <=> s <= qcap
      const int sb = s0 + quad * 4;
      float cmax = -1e30f;
#pragma unroll
      for (int st = 0; st < 4; ++st)
#pragma unroll
        for (int reg = 0; reg < 4; ++reg) {
          const int s = sb + st * 16 + reg;
          const float v = (s <= qcap) ? S[qs][st][reg] : -1e30f;
          S[qs][st][reg] = v;
          cmax = fmaxf(cmax, v);
        }
      cmax = fmaxf(cmax, __shfl_xor(cmax, 16));
      cmax = fmaxf(cmax, __shfl_xor(cmax, 32));
      const float mnew = fmaxf(mrow[qs], cmax);  // finite: chunk has a valid key
      const float alpha = __expf(mrow[qs] - mnew);
      mrow[qs] = mnew;
      float rsum = 0.f;
      u32 pk[4][2];
#pragma unroll
      for (int st = 0; st < 4; ++st) {
        const float p0 = __expf(S[qs][st][0] - mnew);
        const float p1 = __expf(S[qs][st][1] - mnew);
        const float p2 = __expf(S[qs][st][2] - mnew);
        const float p3 = __expf(S[qs][st][3] - mnew);
        rsum += (p0 + p1) + (p2 + p3);
        pk[st][0] = pack2(p0, p1);
        pk[st][1] = pack2(p2, p3);
      }
      rsum += __shfl_xor(rsum, 16);
      rsum += __shfl_xor(rsum, 32);
      lsum[qs] = lsum[qs] * alpha + rsum;
#pragma unroll
      for (int es = 0; es < 2; ++es)
#pragma unroll
        for (int reg = 0; reg < 4; ++reg) O[qs][es][reg] *= alpha;
      // P -> private per-wave LDS slab (same-wave ordering via lgkmcnt)
#pragma unroll
      for (int st = 0; st < 4; ++st) {
        uint2 d; d.x = pk[st][0]; d.y = pk[st][1];
        *(uint2*)&myPs[(qs * 16 + l16) * 72 + st * 16 + quad * 4] = d;
      }
    }

    // O^T += V^T . P
    __builtin_amdgcn_s_setprio(1);
#pragma unroll
    for (int kc = 0; kc < 2; ++kc) {
      const int ko = kc * 32 + quad * 8;
      const bf16x8 pf0 = ld8(&myPs[l16 * 72 + ko]);
      const bf16x8 pf1 = ld8(&myPs[(16 + l16) * 72 + ko]);
      const bf16x8 vf0 = ld8(Vt + vbase + (size_t)l16 * Tn + s0 + ko);
      const bf16x8 vf1 = ld8(Vt + vbase + (size_t)(16 + l16) * Tn + s0 + ko);
      O[0][0] = mfma16(vf0, pf0, O[0][0]);
      O[0][1] = mfma16(vf1, pf0, O[0][1]);
      O[1][0] = mfma16(vf0, pf1, O[1][0]);
      O[1][1] = mfma16(vf1, pf1, O[1][1]);
    }
    __builtin_amdgcn_s_setprio(0);
  }

  // epilogue: lane q = qs*16+l16, e = es*16+quad*4+reg
#pragma unroll
  for (int qs = 0; qs < 2; ++qs) {
    const float linv = 1.0f / lsum[qs];
    const int t = q0 + qs * 16 + l16;
    const size_t ob = (((size_t)b * Tn + t) * Mn + mm) * Pn + h * 32 + quad * 4;
#pragma unroll
    for (int es = 0; es < 2; ++es) {
      float4 o;
      o.x = O[qs][es][0] * linv; o.y = O[qs][es][1] * linv;
      o.z = O[qs][es][2] * linv; o.w = O[qs][es][3] * linv;
      *(float4*)&out[ob + es * 16] = o;
    }
  }
}

// ------------------------------------------------------------------ launch ---
extern "C" void kernel_launch(void* const* d_in, const int* in_sizes, int n_in,
                              void* d_out, int out_size, void* d_ws, size_t ws_size,
                              hipStream_t stream) {
  const float* inp = (const float*)d_in[0];
  const float* pos = (const float*)d_in[1];
  const void* mask = d_in[2];
  const float* Wq  = (const float*)d_in[3];
  const float* Bq  = (const float*)d_in[4];
  const float* Wk  = (const float*)d_in[5];
  const float* Bk  = (const float*)d_in[6];
  const float* Wv  = (const float*)d_in[7];
  const float* Bv  = (const float*)d_in[8];
  const float* Wqt = (const float*)d_in[9];
  const float* Bqt = (const float*)d_in[10];
  const float* Wkt = (const float*)d_in[11];
  const float* Bkt = (const float*)d_in[12];
  float* out = (float*)d_out;

  const size_t nA = (size_t)Bn * Mn * Hn * Tn * 32;  // 4.19M elems per array
  u16* Qa = (u16*)d_ws;
  u16* Ka = Qa + nA;
  u16* Qb = Ka + nA;
  u16* Kb = Qb + nA;
  u16* Vt = Kb + nA;

  proj_merged<<<512, 256, 0, stream>>>(
      inp, pos, Wq, Wk, Wv, Wqt, Wkt, Bq, Bk, Bv, Bqt, Bkt,
      Qa, Ka, Qb, Kb, Vt);
  attn_flash<<<1024, 256, 0, stream>>>(mask, Qa, Ka, Qb, Kb, Vt, out);
}